// Round 3
// baseline (208.619 us; speedup 1.0000x reference)
//
#include <hip/hip_runtime.h>
#include <stdint.h>

// CycleFC 1w1a: out[b,o,h,w] = sum_c sign(x)[b,c,h,w+off(c)] * sign(W)[o,c] + bias[o]
// off(c) = (c+3)%7 - 3, zero-pad OOB. B=64, C=O=384, H=W=32.
//
// Binary-GEMM: pack signs (bit=1 iff <0) into 6 u64 words; out = bias2 - 2*popc(G^WB).
// bias2t[w][o] = bias[o] + Nvalid(w) + 2*popc(WB & ~V(w)) precomputed in prep.
//
// R8: R7 (1 pixel-group per 48B weight fetch) regressed 71->81us: latency-bound,
// per-wave chain = 64 fetch-groups x ~500cy. Restore+extend R5's key property:
// 4 pixel-groups per weight fetch (~200cy VALU per fetch ~= s_load L2 latency,
// self-hiding). Block = (b, 8 rows, o-half), 384 thr = 6 waves, one barrier.
// Pack: pre-transpose cycle shift (logical-shift zero-fill == OOB pad) +
// 5-step shfl_xor 32x32 bit transpose (both verified in R7). LDS 12KB, R5's
// [r][w][j] u64 layout -> ulonglong2 x3 fragment reads.

#define IN_CH 384
#define HH 32
#define WW 32
#define BB 64
#define HRB 8  // rows per block

constexpr uint64_t P7(int t) {
  uint64_t m = 0;
  for (int k = 0; k < 64; ++k)
    if (k % 7 == t) m |= (1ull << k);
  return m;
}
__device__ __constant__ uint64_t Pm[7] = {P7(0), P7(1), P7(2), P7(3), P7(4), P7(5), P7(6)};

// ---------------- prep: one block (1 wave) per output channel o --------------
__global__ __launch_bounds__(64) void cyc_prep(const float* __restrict__ wgt,
                                               const float* __restrict__ bias,
                                               uint64_t* __restrict__ wbg,
                                               float* __restrict__ bias2t) {
  const int o = blockIdx.x;
  const int lane = threadIdx.x;
  __shared__ uint64_t wb_sh[6];
#pragma unroll
  for (int j = 0; j < 6; ++j) {
    uint64_t m = __ballot(wgt[o * IN_CH + j * 64 + lane] < 0.0f);
    if (lane == 0) wb_sh[j] = m;
  }
  __syncthreads();
  if (lane < 6) wbg[o * 6 + lane] = wb_sh[lane];
  if (lane < WW) {
    const int w = lane;
    int nv = 0, corr = 0;
#pragma unroll
    for (int j = 0; j < 6; ++j) {
      uint64_t V = 0;
#pragma unroll
      for (int d = -3; d <= 3; ++d) {
        int wd = w + d;
        if (wd >= 0 && wd < WW) V |= Pm[(d - j + 14) % 7];
      }
      nv += __popcll(V);
      corr += __popcll(wb_sh[j] & ~V);
    }
    // layout [w][o]: gemm lanes load 32 contiguous floats per o-group
    bias2t[w * IN_CH + o] = bias[o] + (float)nv + 2.0f * (float)corr;
  }
}

// ------- fused main: block = (b, 8 rows, o-half), 384 thr = 6 waves ----------
__global__ __launch_bounds__(384, 3) void cyc_fused(const float* __restrict__ x,
                                                    const uint64_t* __restrict__ wbg,
                                                    const float* __restrict__ bias2t,
                                                    float* __restrict__ out) {
  __shared__ uint64_t sh_G[HRB][WW][6];  // 12288 B; u64 word j = channels j*64+..
  const int t = threadIdx.x;
  const int bid = blockIdx.x;          // grid = 64*4*2 = 512
  const int oh = bid & 1;
  const int hgrp = (bid >> 1) & 3;
  const int b = bid >> 3;
  const int h0 = hgrp * HRB;
  const int wave = t >> 6, lane = t & 63;

  // ---- pack: wave j handles channels c = j*64 + lane, rows h0..h0+7.
  {
    const int j = wave;
    const int c = j * 64 + lane;
    const int off = ((c % 7 + 3) % 7) - 3;  // in [-3,3]
    const uint32_t shr = (off > 0) ? (uint32_t)off : 0u;
    const uint32_t shl = (off < 0) ? (uint32_t)(-off) : 0u;
    uint32_t* shw = (uint32_t*)sh_G;
    const int h = lane >> 5, wcol = lane & 31;
#pragma unroll
    for (int r = 0; r < HRB; ++r) {
      const float4* xp = reinterpret_cast<const float4*>(
          x + (size_t)((b * IN_CH + c) * HH + h0 + r) * WW);
      uint32_t myw = 0;
#pragma unroll
      for (int i = 0; i < 8; ++i) {
        float4 v = xp[i];
        myw |= (v.x < 0.0f ? 1u : 0u) << (i * 4 + 0);
        myw |= (v.y < 0.0f ? 1u : 0u) << (i * 4 + 1);
        myw |= (v.z < 0.0f ? 1u : 0u) << (i * 4 + 2);
        myw |= (v.w < 0.0f ? 1u : 0u) << (i * 4 + 3);
      }
      // pre-transpose cycle shift: bit w := myw bit (w+off); zero-fill == OOB pad
      uint32_t s = (myw >> shr) << shl;  // one of shr/shl is 0
      // 5-step 32x32 bit transpose across each 32-lane half (verified R7).
      // After: lane (h,wcol) holds bit k = shifted sign of ch j*64+h*32+k @ col wcol.
      constexpr uint32_t Mt[5] = {0xFFFF0000u, 0xFF00FF00u, 0xF0F0F0F0u,
                                  0xCCCCCCCCu, 0xAAAAAAAAu};
#pragma unroll
      for (int stp = 0; stp < 5; ++stp) {
        const int js = 16 >> stp;
        const uint32_t M = Mt[stp];
        uint32_t y = __shfl_xor(s, js);
        s = (lane & js) ? ((s & M) | ((y >> js) & ~M))
                        : ((s & ~M) | ((y << js) & M));
      }
      // u32 half h of u64 sh_G[r][wcol][j]
      shw[((r * WW + wcol) * 6 + j) * 2 + h] = s;
    }
  }
  __syncthreads();

  // ---- gemm: wave og owns 32 output channels of this o-half.
  // lane = (r2, w) covers 4 pixels: rows h0 + {r2, 2+r2, 4+r2, 6+r2}, col w.
  const int og = __builtin_amdgcn_readfirstlane(wave);
  const int w = lane & 31, r2 = lane >> 5;
  uint64_t g[4][6];
#pragma unroll
  for (int p = 0; p < 4; ++p) {
    const ulonglong2* gv =
        reinterpret_cast<const ulonglong2*>(&sh_G[p * 2 + r2][w][0]);
    ulonglong2 a0 = gv[0], a1 = gv[1], a2 = gv[2];
    g[p][0] = a0.x; g[p][1] = a0.y; g[p][2] = a1.x;
    g[p][3] = a1.y; g[p][4] = a2.x; g[p][5] = a2.y;
  }
  const int ob = oh * 192 + og * 32;
  float bb[32];
  {
    const float4* bsrc = reinterpret_cast<const float4*>(bias2t + w * IN_CH + ob);
    float4* bdst = reinterpret_cast<float4*>(bb);
#pragma unroll
    for (int i = 0; i < 8; ++i) bdst[i] = bsrc[i];
  }
  const uint64_t* wp = wbg + (size_t)ob * 6;
  // store row h0+p*2+r2, col w  ->  base + p*64 + i*1024; lanes span 256B
  float* op = out + ((size_t)b * IN_CH + ob) * (HH * WW) + h0 * WW + lane;
#pragma unroll
  for (int i = 0; i < 32; ++i) {
    const uint64_t w0 = wp[i * 6 + 0], w1 = wp[i * 6 + 1], w2 = wp[i * 6 + 2];
    const uint64_t w3 = wp[i * 6 + 3], w4 = wp[i * 6 + 4], w5 = wp[i * 6 + 5];
    int m0 = __popcll(g[0][0] ^ w0) + __popcll(g[0][1] ^ w1) + __popcll(g[0][2] ^ w2) +
             __popcll(g[0][3] ^ w3) + __popcll(g[0][4] ^ w4) + __popcll(g[0][5] ^ w5);
    int m1 = __popcll(g[1][0] ^ w0) + __popcll(g[1][1] ^ w1) + __popcll(g[1][2] ^ w2) +
             __popcll(g[1][3] ^ w3) + __popcll(g[1][4] ^ w4) + __popcll(g[1][5] ^ w5);
    int m2 = __popcll(g[2][0] ^ w0) + __popcll(g[2][1] ^ w1) + __popcll(g[2][2] ^ w2) +
             __popcll(g[2][3] ^ w3) + __popcll(g[2][4] ^ w4) + __popcll(g[2][5] ^ w5);
    int m3 = __popcll(g[3][0] ^ w0) + __popcll(g[3][1] ^ w1) + __popcll(g[3][2] ^ w2) +
             __popcll(g[3][3] ^ w3) + __popcll(g[3][4] ^ w4) + __popcll(g[3][5] ^ w5);
    op[i * (HH * WW) + 0]   = bb[i] - 2.0f * (float)m0;
    op[i * (HH * WW) + 64]  = bb[i] - 2.0f * (float)m1;
    op[i * (HH * WW) + 128] = bb[i] - 2.0f * (float)m2;
    op[i * (HH * WW) + 192] = bb[i] - 2.0f * (float)m3;
  }
}

extern "C" void kernel_launch(void* const* d_in, const int* in_sizes, int n_in,
                              void* d_out, int out_size, void* d_ws, size_t ws_size,
                              hipStream_t stream) {
  const float* x = (const float*)d_in[0];
  const float* wgt = (const float*)d_in[1];
  const float* bias = (const float*)d_in[2];
  float* out = (float*)d_out;

  // ws layout: wbg @ 0 (18432 B), bias2t @ 18432 (49152 B)
  uint64_t* wbg = (uint64_t*)d_ws;
  float* bias2t = (float*)((char*)d_ws + 18432);

  cyc_prep<<<IN_CH, 64, 0, stream>>>(wgt, bias, wbg, bias2t);
  cyc_fused<<<BB * (HH / HRB) * 2, 384, 0, stream>>>(x, wbg, bias2t, out);
}

// Round 4
// 196.853 us; speedup vs baseline: 1.0598x; 1.0598x over previous
//
#include <hip/hip_runtime.h>
#include <stdint.h>

// CycleFC 1w1a: out[b,o,h,w] = sum_c sign(x)[b,c,h,w+off(c)] * sign(W)[o,c] + bias[o]
// off(c) = (c+3)%7 - 3, zero-pad OOB. B=64, C=O=384, H=W=32.
//
// Binary-GEMM: pack signs (bit=1 iff <0) into 6 u64 words; out = bias2 - 2*popc(G^WB).
// bias2t[w][o] = bias[o] + Nvalid(w) + 2*popc(WB & ~V(w)) precomputed in prep.
//
// R9: spill diagnosis. R5/R7/R8 all report VGPR_Count 32-40 while the gemm
// live set (g fragments + bb[32]) needs 56-128 regs -> fragments & bias were
// in SCRATCH; inner loop = per-iter scratch reads (~300-900cy) -> waves 95%
// stalled, VALUBusy pinned ~28%, wall ~invariant at 71-82us. Fix: R5 block
// structure (12 waves, HR=4, no o-split, grid 512, 24 waves/CU) + R8's cheap
// pack (pre-transpose shift + shfl_xor butterfly) + spill-proof gemm:
// 12 NAMED u64 g scalars, bias tiled 8-at-a-time (2x float4, static index).

#define IN_CH 384
#define HH 32
#define WW 32
#define BB 64
#define HR 4  // rows per block

constexpr uint64_t P7(int t) {
  uint64_t m = 0;
  for (int k = 0; k < 64; ++k)
    if (k % 7 == t) m |= (1ull << k);
  return m;
}
__device__ __constant__ uint64_t Pm[7] = {P7(0), P7(1), P7(2), P7(3), P7(4), P7(5), P7(6)};

// ---------------- prep: one block (1 wave) per output channel o --------------
__global__ __launch_bounds__(64) void cyc_prep(const float* __restrict__ wgt,
                                               const float* __restrict__ bias,
                                               uint64_t* __restrict__ wbg,
                                               float* __restrict__ bias2t) {
  const int o = blockIdx.x;
  const int lane = threadIdx.x;
  __shared__ uint64_t wb_sh[6];
#pragma unroll
  for (int j = 0; j < 6; ++j) {
    uint64_t m = __ballot(wgt[o * IN_CH + j * 64 + lane] < 0.0f);
    if (lane == 0) wb_sh[j] = m;
  }
  __syncthreads();
  if (lane < 6) wbg[o * 6 + lane] = wb_sh[lane];
  if (lane < WW) {
    const int w = lane;
    int nv = 0, corr = 0;
#pragma unroll
    for (int j = 0; j < 6; ++j) {
      uint64_t V = 0;
#pragma unroll
      for (int d = -3; d <= 3; ++d) {
        int wd = w + d;
        if (wd >= 0 && wd < WW) V |= Pm[(d - j + 14) % 7];
      }
      nv += __popcll(V);
      corr += __popcll(wb_sh[j] & ~V);
    }
    // layout [w][o]: gemm lanes read contiguous float4s per o-tile
    bias2t[w * IN_CH + o] = bias[o] + (float)nv + 2.0f * (float)corr;
  }
}

// ------- fused main: block = (b, 4 rows), 768 thr = 12 waves -----------------
__global__ __launch_bounds__(768) void cyc_fused(const float* __restrict__ x,
                                                 const uint64_t* __restrict__ wbg,
                                                 const float* __restrict__ bias2t,
                                                 float* __restrict__ out) {
  __shared__ uint64_t sh_G[HR][WW][6];  // 6144 B; u64 word j = channels j*64+..
  const int t = threadIdx.x;
  const int b = blockIdx.x >> 3;        // grid = 64*8 = 512
  const int h0 = (blockIdx.x & 7) * HR;
  const int wave = t >> 6, lane = t & 63;

  // ---- pack: 24 (r,j) tasks over 12 waves (2 each), butterfly transpose.
  {
    uint32_t* shw = (uint32_t*)sh_G;
    const int h = lane >> 5, wcol = lane & 31;
#pragma unroll
    for (int p = 0; p < 2; ++p) {
      const int tau = wave + p * 12;
      const int r = tau / 6, j = tau % 6;
      const int c = j * 64 + lane;
      const int off = ((c % 7 + 3) % 7) - 3;  // in [-3,3]
      const uint32_t shr = (off > 0) ? (uint32_t)off : 0u;
      const uint32_t shl = (off < 0) ? (uint32_t)(-off) : 0u;
      const float4* xp = reinterpret_cast<const float4*>(
          x + (size_t)((b * IN_CH + c) * HH + h0 + r) * WW);
      uint32_t myw = 0;
#pragma unroll
      for (int i = 0; i < 8; ++i) {
        float4 v = xp[i];
        myw |= (v.x < 0.0f ? 1u : 0u) << (i * 4 + 0);
        myw |= (v.y < 0.0f ? 1u : 0u) << (i * 4 + 1);
        myw |= (v.z < 0.0f ? 1u : 0u) << (i * 4 + 2);
        myw |= (v.w < 0.0f ? 1u : 0u) << (i * 4 + 3);
      }
      // pre-transpose cycle shift: bit w := myw bit (w+off); zero-fill == OOB pad
      uint32_t s = (myw >> shr) << shl;  // one of shr/shl is 0
      // 5-step 32x32 bit transpose across each 32-lane half (verified R7/R8).
      constexpr uint32_t Mt[5] = {0xFFFF0000u, 0xFF00FF00u, 0xF0F0F0F0u,
                                  0xCCCCCCCCu, 0xAAAAAAAAu};
#pragma unroll
      for (int stp = 0; stp < 5; ++stp) {
        const int js = 16 >> stp;
        const uint32_t M = Mt[stp];
        uint32_t y = __shfl_xor(s, js);
        s = (lane & js) ? ((s & M) | ((y >> js) & ~M))
                        : ((s & ~M) | ((y << js) & M));
      }
      // u32 half h of u64 sh_G[r][wcol][j]
      shw[((r * WW + wcol) * 6 + j) * 2 + h] = s;
    }
  }
  __syncthreads();

  // ---- gemm: wave og owns 32 o-channels; lane = (r2, w) covers rows
  // h0+r2 (A) and h0+2+r2 (B). All state in NAMED scalars -> no scratch.
  const int og = __builtin_amdgcn_readfirstlane(wave);
  const int w = lane & 31, r2 = lane >> 5;
  const ulonglong2* gv = reinterpret_cast<const ulonglong2*>(&sh_G[r2][w][0]);
  const ulonglong2 a0 = gv[0], a1 = gv[1], a2 = gv[2];
  const ulonglong2* hv = reinterpret_cast<const ulonglong2*>(&sh_G[2 + r2][w][0]);
  const ulonglong2 b0 = hv[0], b1 = hv[1], b2 = hv[2];
  const uint64_t gA0 = a0.x, gA1 = a0.y, gA2 = a1.x, gA3 = a1.y, gA4 = a2.x, gA5 = a2.y;
  const uint64_t gB0 = b0.x, gB1 = b0.y, gB2 = b1.x, gB3 = b1.y, gB4 = b2.x, gB5 = b2.y;

  const float4* bsrc = reinterpret_cast<const float4*>(bias2t + w * IN_CH + og * 32);
  const uint64_t* wp = wbg + (size_t)og * 32 * 6;
  // group A lanes cover (h0+r2)*32+w = h0*32+lane -> 256B contiguous store
  float* opA = out + ((size_t)b * IN_CH + og * 32) * (HH * WW) + h0 * WW + lane;
  float* opB = opA + 2 * WW;

#pragma unroll
  for (int ot = 0; ot < 4; ++ot) {
    const float4 bb0 = bsrc[ot * 2 + 0];
    const float4 bb1 = bsrc[ot * 2 + 1];
    const float bbv[8] = {bb0.x, bb0.y, bb0.z, bb0.w,
                          bb1.x, bb1.y, bb1.z, bb1.w};
#pragma unroll
    for (int i = 0; i < 8; ++i) {
      const int oi = ot * 8 + i;
      const uint64_t w0 = wp[oi * 6 + 0], w1 = wp[oi * 6 + 1], w2 = wp[oi * 6 + 2];
      const uint64_t w3 = wp[oi * 6 + 3], w4 = wp[oi * 6 + 4], w5 = wp[oi * 6 + 5];
      int mmA = __popcll(gA0 ^ w0) + __popcll(gA1 ^ w1) + __popcll(gA2 ^ w2) +
                __popcll(gA3 ^ w3) + __popcll(gA4 ^ w4) + __popcll(gA5 ^ w5);
      int mmB = __popcll(gB0 ^ w0) + __popcll(gB1 ^ w1) + __popcll(gB2 ^ w2) +
                __popcll(gB3 ^ w3) + __popcll(gB4 ^ w4) + __popcll(gB5 ^ w5);
      opA[oi * (HH * WW)] = bbv[i] - 2.0f * (float)mmA;
      opB[oi * (HH * WW)] = bbv[i] - 2.0f * (float)mmB;
    }
  }
}

extern "C" void kernel_launch(void* const* d_in, const int* in_sizes, int n_in,
                              void* d_out, int out_size, void* d_ws, size_t ws_size,
                              hipStream_t stream) {
  const float* x = (const float*)d_in[0];
  const float* wgt = (const float*)d_in[1];
  const float* bias = (const float*)d_in[2];
  float* out = (float*)d_out;

  // ws layout: wbg @ 0 (18432 B), bias2t @ 18432 (49152 B)
  uint64_t* wbg = (uint64_t*)d_ws;
  float* bias2t = (float*)((char*)d_ws + 18432);

  cyc_prep<<<IN_CH, 64, 0, stream>>>(wgt, bias, wbg, bias2t);
  cyc_fused<<<BB * (HH / HR), 768, 0, stream>>>(x, wbg, bias2t, out);
}